// Round 1
// baseline (46.861 us; speedup 1.0000x reference)
//
#include <hip/hip_runtime.h>
#include <hip/hip_bf16.h>
#include <cmath>

// Problem constants (fixed by the reference): B=8, S=4096, D=768, N=4.
#define DDIM 768
#define NLIN 4
#define F4_PER_ROW (DDIM / 4)          // 192 float4 per row
#define F4_PER_LANE (F4_PER_ROW / 64)  // 3 float4 per lane per row

__device__ __forceinline__ float fast_sigmoid(float z) {
    return 1.0f / (1.0f + __expf(-z));
}

__global__ __launch_bounds__(256) void ScaleNumEmbed_25726854103624_kernel(
    const float* __restrict__ embeds,   // [rows, D]
    const float* __restrict__ numbers,  // [rows]
    const int*   __restrict__ isnum,    // [rows] 0/1
    const float* __restrict__ W,        // [N, D]
    const float* __restrict__ bias,     // [N, D]
    float* __restrict__ out,            // [rows, D]
    int rows)
{
    const int lane   = threadIdx.x & 63;
    const int wave   = (int)((blockIdx.x * blockDim.x + threadIdx.x) >> 6);
    const int nwaves = (int)((gridDim.x * blockDim.x) >> 6);

    // Preload this lane's W/b fragments into registers (static indexing only).
    // Lane handles float4 indices {lane, lane+64, lane+128} within each row.
    float wreg[F4_PER_LANE][NLIN][4];
    float breg[F4_PER_LANE][NLIN][4];
#pragma unroll
    for (int k = 0; k < F4_PER_LANE; ++k) {
        const int d0 = (lane + 64 * k) * 4;
#pragma unroll
        for (int n = 0; n < NLIN; ++n) {
            const float4 wv = *reinterpret_cast<const float4*>(W    + n * DDIM + d0);
            const float4 bv = *reinterpret_cast<const float4*>(bias + n * DDIM + d0);
            wreg[k][n][0] = wv.x; wreg[k][n][1] = wv.y;
            wreg[k][n][2] = wv.z; wreg[k][n][3] = wv.w;
            breg[k][n][0] = bv.x; breg[k][n][1] = bv.y;
            breg[k][n][2] = bv.z; breg[k][n][3] = bv.w;
        }
    }

    for (int row = wave; row < rows; row += nwaves) {
        const bool isn = (isnum[row] != 0);   // wave-uniform
        const float4* src = reinterpret_cast<const float4*>(embeds + (size_t)row * DDIM);
        float4*       dst = reinterpret_cast<float4*>(out + (size_t)row * DDIM);

        if (!isn) {
            // Straight row copy, coalesced float4.
#pragma unroll
            for (int k = 0; k < F4_PER_LANE; ++k) {
                dst[lane + 64 * k] = src[lane + 64 * k];
            }
        } else {
            // number row: never touch embeds.
            const float f = __logf(numbers[row]);
#pragma unroll
            for (int k = 0; k < F4_PER_LANE; ++k) {
                float acc[4];
#pragma unroll
                for (int c = 0; c < 4; ++c) acc[c] = 0.0f;
#pragma unroll
                for (int n = 0; n < NLIN; ++n) {
#pragma unroll
                    for (int c = 0; c < 4; ++c) {
                        acc[c] += fast_sigmoid(fmaf(f, wreg[k][n][c], breg[k][n][c]));
                    }
                }
                float4 o;
                o.x = acc[0]; o.y = acc[1]; o.z = acc[2]; o.w = acc[3];
                dst[lane + 64 * k] = o;
            }
        }
    }
}

extern "C" void kernel_launch(void* const* d_in, const int* in_sizes, int n_in,
                              void* d_out, int out_size, void* d_ws, size_t ws_size,
                              hipStream_t stream) {
    const float* embeds  = (const float*)d_in[0];
    const float* numbers = (const float*)d_in[1];
    const int*   isnum   = (const int*)d_in[2];
    const float* W       = (const float*)d_in[3];
    const float* bias    = (const float*)d_in[4];
    float*       out     = (float*)d_out;

    const int rows = in_sizes[1];  // B*S = 32768

    const int block = 256;
    const int grid  = 1024;  // 4096 waves, 8 rows each via grid-stride
    ScaleNumEmbed_25726854103624_kernel<<<grid, block, 0, stream>>>(
        embeds, numbers, isnum, W, bias, out, rows);
}

// Round 2
// 43.004 us; speedup vs baseline: 1.0897x; 1.0897x over previous
//
#include <hip/hip_runtime.h>
#include <hip/hip_bf16.h>
#include <cmath>

// Problem constants (fixed by the reference): B=8, S=4096, D=768, N=4.
#define DDIM 768
#define NLIN 4
#define BLOCK 192                      // one row per block: 192 threads x float4 = 768 floats

typedef float f32x4 __attribute__((ext_vector_type(4)));

__device__ __forceinline__ float fast_sigmoid(float z) {
    return 1.0f / (1.0f + __expf(-z));
}

__global__ __launch_bounds__(BLOCK) void ScaleNumEmbed_25726854103624_kernel(
    const float* __restrict__ embeds,   // [rows, D]
    const float* __restrict__ numbers,  // [rows]
    const int*   __restrict__ isnum,    // [rows] 0/1
    const float* __restrict__ W,        // [N, D]
    const float* __restrict__ bias,     // [N, D]
    float* __restrict__ out)            // [rows, D]
{
    const int row = blockIdx.x;
    const int t   = threadIdx.x;       // 0..191

    // Issue the row-scalar loads immediately and in parallel (independent).
    const int   isn = isnum[row];
    const float num = numbers[row];

    const f32x4* src = reinterpret_cast<const f32x4*>(embeds + (size_t)row * DDIM);
    f32x4*       dst = reinterpret_cast<f32x4*>(out + (size_t)row * DDIM);

    if (!isn) {
        // Non-number row: streamed copy, one float4 per thread.
        f32x4 v = __builtin_nontemporal_load(src + t);
        __builtin_nontemporal_store(v, dst + t);
    } else {
        // Number row: never touch embeds.
        const float f  = __logf(num);
        const int   d0 = t * 4;
        f32x4 acc = {0.0f, 0.0f, 0.0f, 0.0f};
#pragma unroll
        for (int n = 0; n < NLIN; ++n) {
            const f32x4 wv = *reinterpret_cast<const f32x4*>(W    + n * DDIM + d0);
            const f32x4 bv = *reinterpret_cast<const f32x4*>(bias + n * DDIM + d0);
            acc.x += fast_sigmoid(fmaf(f, wv.x, bv.x));
            acc.y += fast_sigmoid(fmaf(f, wv.y, bv.y));
            acc.z += fast_sigmoid(fmaf(f, wv.z, bv.z));
            acc.w += fast_sigmoid(fmaf(f, wv.w, bv.w));
        }
        __builtin_nontemporal_store(acc, dst + t);
    }
}

extern "C" void kernel_launch(void* const* d_in, const int* in_sizes, int n_in,
                              void* d_out, int out_size, void* d_ws, size_t ws_size,
                              hipStream_t stream) {
    const float* embeds  = (const float*)d_in[0];
    const float* numbers = (const float*)d_in[1];
    const int*   isnum   = (const int*)d_in[2];
    const float* W       = (const float*)d_in[3];
    const float* bias    = (const float*)d_in[4];
    float*       out     = (float*)d_out;

    const int rows = in_sizes[1];  // B*S = 32768

    ScaleNumEmbed_25726854103624_kernel<<<rows, BLOCK, 0, stream>>>(
        embeds, numbers, isnum, W, bias, out);
}